// Round 1
// baseline (294.006 us; speedup 1.0000x reference)
//
#include <hip/hip_runtime.h>

// Problem constants (from reference)
#define BATCH 32
#define CCH 3
#define H_TEX 512
#define W_TEX 512
#define N_TEX (H_TEX * W_TEX * CCH)   // 786432 per-sample flat texture (channels-last)
#define OH 128
#define OW 64
#define M_OUT (OH * OW * CCH)         // 24576 rows per sample (channels-last)
#define NNZ 98304
#define OUT_ELEMS (BATCH * CCH * OH * OW)  // 786432 (result), same count for mask

// Kernel 1: zero the result half of d_out, copy mask into the second half.
// Vectorized float4: OUT_ELEMS/4 = 196608 threads.
__global__ void init_out_kernel(float* __restrict__ out,
                                const float* __restrict__ mask) {
    int i = blockIdx.x * blockDim.x + threadIdx.x;
    if (i < OUT_ELEMS / 4) {
        float4* res4  = reinterpret_cast<float4*>(out);
        float4* msk4o = reinterpret_cast<float4*>(out + OUT_ELEMS);
        const float4* msk4i = reinterpret_cast<const float4*>(mask);
        res4[i]  = make_float4(0.f, 0.f, 0.f, 0.f);
        msk4o[i] = msk4i[i];
    }
}

// Kernel 2: gather + atomic scatter.
// out[b, c_out, p_out] += vals[b,k] * x[b, c_in, p_in]
//   where col = p_in*C + c_in (channels-last), row = p_out*C + c_out.
__global__ void scatter_kernel(const float* __restrict__ x,
                               const int*   __restrict__ rows,
                               const int*   __restrict__ cols,
                               const float* __restrict__ vals,
                               float* __restrict__ out) {
    int gid = blockIdx.x * blockDim.x + threadIdx.x;
    if (gid >= BATCH * NNZ) return;
    int b = gid / NNZ;                 // NNZ % 256 == 0 -> wave-uniform b

    int   r   = rows[gid];
    int   col = cols[gid];
    float v   = vals[gid];

    // gather from x (B, C, H, W): channels-last col -> channels-first index
    int c_in  = col % CCH;
    int p_in  = col / CCH;             // h*W + w
    float xv = x[(size_t)b * N_TEX + (size_t)c_in * (H_TEX * W_TEX) + p_in];

    // scatter to out (B, C, OH, OW): channels-last row -> channels-first index
    int c_out = r % CCH;
    int p_out = r / CCH;               // oh*OW + ow
    atomicAdd(&out[(size_t)b * (CCH * OH * OW) + (size_t)c_out * (OH * OW) + p_out],
              v * xv);
}

extern "C" void kernel_launch(void* const* d_in, const int* in_sizes, int n_in,
                              void* d_out, int out_size, void* d_ws, size_t ws_size,
                              hipStream_t stream) {
    const float* x    = (const float*)d_in[0];
    const int*   rows = (const int*)  d_in[1];
    const int*   cols = (const int*)  d_in[2];
    const float* vals = (const float*)d_in[3];
    const float* mask = (const float*)d_in[4];
    float* out = (float*)d_out;

    {
        int n = OUT_ELEMS / 4;                    // 196608
        int block = 256;
        int grid = (n + block - 1) / block;       // 768
        init_out_kernel<<<grid, block, 0, stream>>>(out, mask);
    }
    {
        int n = BATCH * NNZ;                      // 3145728
        int block = 256;
        int grid = (n + block - 1) / block;       // 12288
        scatter_kernel<<<grid, block, 0, stream>>>(x, rows, cols, vals, out);
    }
}

// Round 2
// 287.712 us; speedup vs baseline: 1.0219x; 1.0219x over previous
//
#include <hip/hip_runtime.h>

// Problem constants
#define BATCH 32
#define CCH 3
#define HW_TEX (512 * 512)
#define N_TEX (HW_TEX * CCH)          // 786432 per-sample flat texture (channels-last)
#define OH 128
#define OW 64
#define P_OUT (OH * OW)               // 8192 spatial positions per sample
#define M_OUT (P_OUT * CCH)           // 24576 rows per sample (channels-last)
#define NNZ 98304
#define OUT_ELEMS (BATCH * M_OUT)     // 786432 result elems (mask is same count)

#define CHUNKS 8                      // row chunks per sample
#define ROWS_PER_CHUNK (M_OUT / CHUNKS)  // 3072 -> 12 KB LDS
#define P_PER_CHUNK (P_OUT / CHUNKS)     // 1024
#define BLOCK 1024                    // 16 waves

// One workgroup per (sample, row-chunk). Exclusive ownership of the output
// rows -> LDS accumulation + plain coalesced stores, ZERO global atomics.
__global__ __launch_bounds__(BLOCK) void spmm_chunk_kernel(
    const float* __restrict__ x,
    const int*   __restrict__ rows,
    const int*   __restrict__ cols,
    const float* __restrict__ vals,
    const float* __restrict__ mask,
    float* __restrict__ out) {
    __shared__ float acc[ROWS_PER_CHUNK];

    const int blk = blockIdx.x;
    const int s   = blk / CHUNKS;     // sample
    const int c   = blk % CHUNKS;     // row chunk
    const int t   = threadIdx.x;
    const int rbase = c * ROWS_PER_CHUNK;

#pragma unroll
    for (int j = 0; j < ROWS_PER_CHUNK / BLOCK; ++j)  // 3 per thread
        acc[t + j * BLOCK] = 0.0f;
    __syncthreads();

    const int*   rs = rows + (size_t)s * NNZ;
    const int*   cs = cols + (size_t)s * NNZ;
    const float* vs = vals + (size_t)s * NNZ;
    const float* xs = x    + (size_t)s * N_TEX;

    // Scan all nnz of this sample; keep only rows in our chunk (~1/8 lanes).
#pragma unroll 4
    for (int i = t; i < NNZ; i += BLOCK) {            // exactly 96 iterations
        int r = rs[i];
        unsigned lr = (unsigned)(r - rbase);
        if (lr < (unsigned)ROWS_PER_CHUNK) {
            int   col = cs[i];
            float v   = vs[i];
            int c_in = col % CCH;                     // channels-last -> CHW
            int p_in = col / CCH;
            float xv = xs[c_in * HW_TEX + p_in];
            atomicAdd(&acc[lr], v * xv);              // ds_add_f32 (LDS atomic)
        }
    }
    __syncthreads();

    // Epilogue: chunk rows [rbase, rbase+3072) map to 3 contiguous 4 KB spans
    // of the transposed output: out[s][ch][c*1024 + t], t in [0,1024).
    const size_t outbase = (size_t)s * M_OUT;
#pragma unroll
    for (int ch = 0; ch < CCH; ++ch) {
        // LDS read stride 3 (odd) -> bank-conflict-free; store coalesced.
        out[outbase + (size_t)ch * P_OUT + c * P_PER_CHUNK + t] = acc[t * CCH + ch];
    }

    // Mask passthrough: 256 blocks x 3072 floats = 786432.
    {
        float*       mout = out + OUT_ELEMS;
        const int    base = blk * ROWS_PER_CHUNK;
#pragma unroll
        for (int j = 0; j < ROWS_PER_CHUNK / BLOCK; ++j)
            mout[base + j * BLOCK + t] = mask[base + j * BLOCK + t];
    }
}

extern "C" void kernel_launch(void* const* d_in, const int* in_sizes, int n_in,
                              void* d_out, int out_size, void* d_ws, size_t ws_size,
                              hipStream_t stream) {
    const float* x    = (const float*)d_in[0];
    const int*   rows = (const int*)  d_in[1];
    const int*   cols = (const int*)  d_in[2];
    const float* vals = (const float*)d_in[3];
    const float* mask = (const float*)d_in[4];
    float* out = (float*)d_out;

    spmm_chunk_kernel<<<BATCH * CHUNKS, BLOCK, 0, stream>>>(x, rows, cols, vals, mask, out);
}

// Round 3
// 285.777 us; speedup vs baseline: 1.0288x; 1.0068x over previous
//
#include <hip/hip_runtime.h>

// Problem constants
#define BATCH 32
#define CCH 3
#define HW_TEX (512 * 512)
#define N_TEX (HW_TEX * CCH)          // 786432 per-sample flat texture (channels-last)
#define OH 128
#define OW 64
#define P_OUT (OH * OW)               // 8192
#define M_OUT (P_OUT * CCH)           // 24576 rows per sample (channels-last)
#define NNZ 98304
#define OUT_ELEMS (BATCH * M_OUT)     // 786432

#define NXCD 8
#define SAMPLES_PER_XCD (BATCH / NXCD)   // 4
#define CHUNKS 8                          // row chunks per sample
#define RPC (M_OUT / CHUNKS)              // 3072 rows -> 12 KB LDS
#define QSPLIT 4                          // nnz quarters
#define SEG (NNZ / QSPLIT)                // 24576
#define BLOCK 1024

#define WS_NEEDED ((size_t)BATCH * CHUNKS * QSPLIT * RPC * 4)  // 12.58 MB

// ---------------- Main path: XCD-affine scan with LDS accumulation ----------
// grid 256 = 8 XCDs x 32 slots; slot -> (chunk c, nnz-quarter q).
// Each block loops its XCD's 4 samples SEQUENTIALLY so the XCD's L2 holds
// one sample's x slab (+indices) at a time -> gathers hit L2.
__global__ __launch_bounds__(BLOCK) void scan_kernel(
    const float* __restrict__ x,
    const int*   __restrict__ rows,
    const int*   __restrict__ cols,
    const float* __restrict__ vals,
    float* __restrict__ partial) {
    __shared__ float acc[RPC];

    const int blk  = blockIdx.x;
    const int xcd  = blk & (NXCD - 1);     // hw round-robin: blk%8 -> XCD
    const int slot = blk >> 3;             // 0..31
    const int c    = slot & (CHUNKS - 1);  // row chunk
    const int q    = slot >> 3;            // nnz quarter
    const int t    = threadIdx.x;
    const int rbase = c * RPC;

    for (int ti = 0; ti < SAMPLES_PER_XCD; ++ti) {
        const int s = xcd * SAMPLES_PER_XCD + ti;

#pragma unroll
        for (int j = 0; j < RPC / BLOCK; ++j)   // 3 per thread
            acc[t + j * BLOCK] = 0.0f;
        __syncthreads();

        const int*   rs = rows + (size_t)s * NNZ + (size_t)q * SEG;
        const int*   cs = cols + (size_t)s * NNZ + (size_t)q * SEG;
        const float* vs = vals + (size_t)s * NNZ + (size_t)q * SEG;
        const float* xs = x    + (size_t)s * N_TEX;

#pragma unroll 4
        for (int i = t; i < SEG; i += BLOCK) {  // 24 iterations
            int r = rs[i];
            unsigned lr = (unsigned)(r - rbase);
            if (lr < (unsigned)RPC) {
                int   col = cs[i];
                float v   = vs[i];
                int c_in = col % CCH;
                int p_in = col / CCH;
                atomicAdd(&acc[lr], v * xs[c_in * HW_TEX + p_in]);  // ds_add_f32
            }
        }
        __syncthreads();

        float* pp = partial + (((size_t)s * CHUNKS + c) * QSPLIT + q) * RPC;
#pragma unroll
        for (int j = 0; j < RPC / BLOCK; ++j)
            pp[t + j * BLOCK] = acc[t + j * BLOCK];
        __syncthreads();
    }
}

// Reduce 4 quarter-partials, transform channels-last row -> CHW, copy mask.
__global__ __launch_bounds__(256) void reduce_kernel(
    const float* __restrict__ partial,
    const float* __restrict__ mask,
    float* __restrict__ out) {
    int o = blockIdx.x * 256 + threadIdx.x;
    if (o >= OUT_ELEMS) return;
    int s   = o / M_OUT;
    int rem = o % M_OUT;
    int ch  = rem / P_OUT;
    int p   = rem % P_OUT;
    int rcl = p * CCH + ch;              // channels-last row id
    int c   = rcl / RPC;
    int lr  = rcl % RPC;
    const float* pp = partial + (((size_t)s * CHUNKS + c) * QSPLIT) * RPC + lr;
    out[o] = pp[0] + pp[RPC] + pp[2 * RPC] + pp[3 * RPC];
    out[OUT_ELEMS + o] = mask[o];
}

// ---------------- Fallback (R2): no workspace needed ------------------------
__global__ __launch_bounds__(BLOCK) void spmm_chunk_kernel(
    const float* __restrict__ x,
    const int*   __restrict__ rows,
    const int*   __restrict__ cols,
    const float* __restrict__ vals,
    const float* __restrict__ mask,
    float* __restrict__ out) {
    __shared__ float acc[RPC];
    const int blk = blockIdx.x;
    const int s   = blk / CHUNKS;
    const int c   = blk % CHUNKS;
    const int t   = threadIdx.x;
    const int rbase = c * RPC;
#pragma unroll
    for (int j = 0; j < RPC / BLOCK; ++j) acc[t + j * BLOCK] = 0.0f;
    __syncthreads();
    const int*   rs = rows + (size_t)s * NNZ;
    const int*   cs = cols + (size_t)s * NNZ;
    const float* vs = vals + (size_t)s * NNZ;
    const float* xs = x    + (size_t)s * N_TEX;
#pragma unroll 4
    for (int i = t; i < NNZ; i += BLOCK) {
        int r = rs[i];
        unsigned lr = (unsigned)(r - rbase);
        if (lr < (unsigned)RPC) {
            int   col = cs[i];
            float v   = vs[i];
            int c_in = col % CCH;
            int p_in = col / CCH;
            atomicAdd(&acc[lr], v * xs[c_in * HW_TEX + p_in]);
        }
    }
    __syncthreads();
    const size_t outbase = (size_t)s * M_OUT;
#pragma unroll
    for (int ch = 0; ch < CCH; ++ch)
        out[outbase + (size_t)ch * P_OUT + c * (P_OUT / CHUNKS) + t] = acc[t * CCH + ch];
    {
        float* mout = out + OUT_ELEMS;
        const int base = blk * RPC;
#pragma unroll
        for (int j = 0; j < RPC / BLOCK; ++j)
            mout[base + j * BLOCK + t] = mask[base + j * BLOCK + t];
    }
}

extern "C" void kernel_launch(void* const* d_in, const int* in_sizes, int n_in,
                              void* d_out, int out_size, void* d_ws, size_t ws_size,
                              hipStream_t stream) {
    const float* x    = (const float*)d_in[0];
    const int*   rows = (const int*)  d_in[1];
    const int*   cols = (const int*)  d_in[2];
    const float* vals = (const float*)d_in[3];
    const float* mask = (const float*)d_in[4];
    float* out = (float*)d_out;

    if (ws_size >= WS_NEEDED) {
        float* partial = (float*)d_ws;
        scan_kernel<<<NXCD * 32, BLOCK, 0, stream>>>(x, rows, cols, vals, partial);
        reduce_kernel<<<(OUT_ELEMS + 255) / 256, 256, 0, stream>>>(partial, mask, out);
    } else {
        spmm_chunk_kernel<<<BATCH * CHUNKS, BLOCK, 0, stream>>>(x, rows, cols, vals, mask, out);
    }
}

// Round 4
// 208.511 us; speedup vs baseline: 1.4100x; 1.3706x over previous
//
#include <hip/hip_runtime.h>

// Problem constants
#define BATCH 32
#define CCH 3
#define HW_TEX (512 * 512)
#define N_TEX (HW_TEX * CCH)          // 786432 per-sample flat texture (channels-last)
#define OH 128
#define OW 64
#define P_OUT (OH * OW)               // 8192
#define M_OUT (P_OUT * CCH)           // 24576 rows per sample (96 KB as f32)
#define NNZ 98304
#define OUT_ELEMS (BATCH * M_OUT)     // 786432

#define BLOCK 1024

#define WS_SEG8 ((size_t)32 * 8 * M_OUT * 4)   // 25.17 MB
#define WS_SEG4 ((size_t)32 * 4 * M_OUT * 4)   // 12.58 MB

// ---------------- Full-row LDS scan: no filter, no divergence ---------------
// blk = seg*32 + s  ->  blk%8 = s%8: all blocks of sample s on one XCD.
// Each block: zero 96 KB LDS, stream its nnz segment with int4-batched loads,
// unconditional gather + ds_add_f32, dump partial to ws.
template <int NSEG>
__global__ __launch_bounds__(BLOCK) void scan_full_kernel(
    const float* __restrict__ x,
    const int*   __restrict__ rows,
    const int*   __restrict__ cols,
    const float* __restrict__ vals,
    float* __restrict__ partial) {
    __shared__ __align__(16) float acc[M_OUT];

    const int blk = blockIdx.x;
    const int s   = blk & 31;          // sample
    const int seg = blk >> 5;          // nnz segment
    const int t   = threadIdx.x;

    // zero 96 KB: 6 x float4 per thread
    float4* acc4 = reinterpret_cast<float4*>(acc);
#pragma unroll
    for (int j = 0; j < M_OUT / 4 / BLOCK; ++j)
        acc4[t + j * BLOCK] = make_float4(0.f, 0.f, 0.f, 0.f);
    __syncthreads();

    constexpr int SEGN = NNZ / NSEG;                 // nnz per segment
    const size_t  off  = (size_t)s * NNZ + (size_t)seg * SEGN;
    const int4*   r4 = reinterpret_cast<const int4*>(rows + off);
    const int4*   c4 = reinterpret_cast<const int4*>(cols + off);
    const float4* v4 = reinterpret_cast<const float4*>(vals + off);
    const float*  xs = x + (size_t)s * N_TEX;

#pragma unroll
    for (int j = 0; j < SEGN / (BLOCK * 4); ++j) {   // 3 (NSEG=8) or 6 (NSEG=4)
        int4   r = r4[j * BLOCK + t];
        int4   c = c4[j * BLOCK + t];
        float4 v = v4[j * BLOCK + t];

        float g0 = xs[(c.x % CCH) * HW_TEX + c.x / CCH];
        float g1 = xs[(c.y % CCH) * HW_TEX + c.y / CCH];
        float g2 = xs[(c.z % CCH) * HW_TEX + c.z / CCH];
        float g3 = xs[(c.w % CCH) * HW_TEX + c.w / CCH];

        atomicAdd(&acc[r.x], v.x * g0);
        atomicAdd(&acc[r.y], v.y * g1);
        atomicAdd(&acc[r.z], v.z * g2);
        atomicAdd(&acc[r.w], v.w * g3);
    }
    __syncthreads();

    // dump partial: coalesced float4
    float4* pp = reinterpret_cast<float4*>(partial + (size_t)blk * M_OUT);
#pragma unroll
    for (int j = 0; j < M_OUT / 4 / BLOCK; ++j)
        pp[t + j * BLOCK] = acc4[t + j * BLOCK];
}

// Reduce NSEG partials, channels-last -> CHW transform, mask passthrough.
__global__ __launch_bounds__(256) void reduce_kernel(
    const float* __restrict__ partial,
    const float* __restrict__ mask,
    float* __restrict__ out, int nseg) {
    int tid = blockIdx.x * 256 + threadIdx.x;     // over B*M, channels-last order
    if (tid >= OUT_ELEMS) return;
    int s   = tid / M_OUT;
    int rcl = tid % M_OUT;
    float sum = 0.f;
    for (int seg = 0; seg < nseg; ++seg)
        sum += partial[(size_t)(seg * 32 + s) * M_OUT + rcl];
    int ch = rcl % CCH;
    int p  = rcl / CCH;
    out[(size_t)s * M_OUT + ch * P_OUT + p] = sum;
    out[OUT_ELEMS + tid] = mask[tid];
}

// ---------------- Fallback (R2): no workspace needed ------------------------
#define CHUNKS 8
#define RPC (M_OUT / CHUNKS)
__global__ __launch_bounds__(BLOCK) void spmm_chunk_kernel(
    const float* __restrict__ x,
    const int*   __restrict__ rows,
    const int*   __restrict__ cols,
    const float* __restrict__ vals,
    const float* __restrict__ mask,
    float* __restrict__ out) {
    __shared__ float acc[RPC];
    const int blk = blockIdx.x;
    const int s   = blk / CHUNKS;
    const int c   = blk % CHUNKS;
    const int t   = threadIdx.x;
    const int rbase = c * RPC;
#pragma unroll
    for (int j = 0; j < RPC / BLOCK; ++j) acc[t + j * BLOCK] = 0.0f;
    __syncthreads();
    const int*   rs = rows + (size_t)s * NNZ;
    const int*   cs = cols + (size_t)s * NNZ;
    const float* vs = vals + (size_t)s * NNZ;
    const float* xs = x    + (size_t)s * N_TEX;
#pragma unroll 4
    for (int i = t; i < NNZ; i += BLOCK) {
        int r = rs[i];
        unsigned lr = (unsigned)(r - rbase);
        if (lr < (unsigned)RPC) {
            int   col = cs[i];
            float v   = vs[i];
            atomicAdd(&acc[lr], v * xs[(col % CCH) * HW_TEX + col / CCH]);
        }
    }
    __syncthreads();
    const size_t outbase = (size_t)s * M_OUT;
#pragma unroll
    for (int ch = 0; ch < CCH; ++ch)
        out[outbase + (size_t)ch * P_OUT + c * (P_OUT / CHUNKS) + t] = acc[t * CCH + ch];
    {
        float* mout = out + OUT_ELEMS;
        const int base = blk * RPC;
#pragma unroll
        for (int j = 0; j < RPC / BLOCK; ++j)
            mout[base + j * BLOCK + t] = mask[base + j * BLOCK + t];
    }
}

extern "C" void kernel_launch(void* const* d_in, const int* in_sizes, int n_in,
                              void* d_out, int out_size, void* d_ws, size_t ws_size,
                              hipStream_t stream) {
    const float* x    = (const float*)d_in[0];
    const int*   rows = (const int*)  d_in[1];
    const int*   cols = (const int*)  d_in[2];
    const float* vals = (const float*)d_in[3];
    const float* mask = (const float*)d_in[4];
    float* out = (float*)d_out;

    if (ws_size >= WS_SEG8) {
        float* partial = (float*)d_ws;
        scan_full_kernel<8><<<32 * 8, BLOCK, 0, stream>>>(x, rows, cols, vals, partial);
        reduce_kernel<<<(OUT_ELEMS + 255) / 256, 256, 0, stream>>>(partial, mask, out, 8);
    } else if (ws_size >= WS_SEG4) {
        float* partial = (float*)d_ws;
        scan_full_kernel<4><<<32 * 4, BLOCK, 0, stream>>>(x, rows, cols, vals, partial);
        reduce_kernel<<<(OUT_ELEMS + 255) / 256, 256, 0, stream>>>(partial, mask, out, 4);
    } else {
        spmm_chunk_kernel<<<BATCH * CHUNKS, BLOCK, 0, stream>>>(x, rows, cols, vals, mask, out);
    }
}